// Round 8
// baseline (421.524 us; speedup 1.0000x reference)
//
#include <hip/hip_runtime.h>

#define N_NODES    100000
#define N_EDGES    1600000
#define IN_F       64
#define OUT_F      40
#define N_CLUSTERS 10000

#define BUCK_SHIFT 7                                  // 128 rows per bucket
#define BROWS      128
#define NBUCK      ((N_NODES + BROWS - 1) >> BUCK_SHIFT)   // 782
#define CAP        2560                               // mean 2048, sigma 45 -> +11 sigma
#define TILE_E     4096
#define EPT        (TILE_E / 256)                     // 16 edges per thread

typedef _Float16 half_t;
typedef _Float16 half4_t __attribute__((ext_vector_type(4)));
typedef _Float16 half8_t __attribute__((ext_vector_type(8)));

// ---------------------------------------------------------------- bin scatter (single edge pass)
__global__ __launch_bounds__(256) void bin_scatter_kernel(
        const int* __restrict__ rows, const int* __restrict__ cols,
        int* __restrict__ bcursor, unsigned* __restrict__ bins) {
    __shared__ uint2 se[TILE_E];          // 32 KB, ordered by bucket
    __shared__ int lh[NBUCK];
    __shared__ int lsc[NBUCK];
    __shared__ int lb[NBUCK];
    __shared__ int sc[256];
    int t = threadIdx.x;
    for (int i = t; i < NBUCK; i += 256) lh[i] = 0;
    __syncthreads();
    int e0 = blockIdx.x * TILE_E;
    int r[EPT], c[EPT], rk[EPT];
    #pragma unroll
    for (int k = 0; k < EPT; ++k) {
        int e = e0 + t + k * 256;
        if (e < N_EDGES) {
            r[k] = rows[e]; c[k] = cols[e];
            rk[k] = atomicAdd(&lh[r[k] >> BUCK_SHIFT], 1);
        } else r[k] = -1;
    }
    __syncthreads();
    int b4 = t * 4;
    int a0 = (b4 + 0 < NBUCK) ? lh[b4 + 0] : 0;
    int a1 = (b4 + 1 < NBUCK) ? lh[b4 + 1] : 0;
    int a2 = (b4 + 2 < NBUCK) ? lh[b4 + 2] : 0;
    int a3 = (b4 + 3 < NBUCK) ? lh[b4 + 3] : 0;
    int thr = a0 + a1 + a2 + a3;
    sc[t] = thr;
    __syncthreads();
    for (int off = 1; off < 256; off <<= 1) {
        int a = (t >= off) ? sc[t - off] : 0;
        __syncthreads();
        sc[t] += a;
        __syncthreads();
    }
    int ex = sc[t] - thr;
    if (b4 + 0 < NBUCK) { lsc[b4 + 0] = ex;                lb[b4 + 0] = a0 ? atomicAdd(&bcursor[b4 + 0], a0) : 0; }
    if (b4 + 1 < NBUCK) { lsc[b4 + 1] = ex + a0;           lb[b4 + 1] = a1 ? atomicAdd(&bcursor[b4 + 1], a1) : 0; }
    if (b4 + 2 < NBUCK) { lsc[b4 + 2] = ex + a0 + a1;      lb[b4 + 2] = a2 ? atomicAdd(&bcursor[b4 + 2], a2) : 0; }
    if (b4 + 3 < NBUCK) { lsc[b4 + 3] = ex + a0 + a1 + a2; lb[b4 + 3] = a3 ? atomicAdd(&bcursor[b4 + 3], a3) : 0; }
    __syncthreads();
    #pragma unroll
    for (int k = 0; k < EPT; ++k) {
        if (r[k] >= 0) {
            int bu = r[k] >> BUCK_SHIFT;
            se[lsc[bu] + rk[k]] = make_uint2((unsigned)r[k], (unsigned)c[k]);
        }
    }
    __syncthreads();
    #pragma unroll
    for (int k = 0; k < EPT; ++k) {
        int idx = k * 256 + t;
        if (e0 + idx < N_EDGES) {
            uint2 u = se[idx];
            int bu = (int)(u.x >> BUCK_SHIFT);
            int pos = lb[bu] + (idx - lsc[bu]);
            if (pos < CAP)
                bins[(size_t)bu * CAP + pos] = ((u.x & (BROWS - 1)) << 17) | u.y;
        }
    }
}

// ---------------------------------------------------------------- CSR build per bucket
__global__ __launch_bounds__(256) void csr_build_kernel(
        const unsigned* __restrict__ bins, const int* __restrict__ bcnt,
        int* __restrict__ csr_col, uint2* __restrict__ rowinfo,
        float* __restrict__ dinv, const int* __restrict__ cl,
        int* __restrict__ ccnt) {
    __shared__ int lcnt[BROWS];
    __shared__ int gbeg[BROWS];
    __shared__ int sc[BROWS];
    int b = blockIdx.x, t = threadIdx.x;
    int n = min(bcnt[b], CAP);
    const unsigned* eb = bins + (size_t)b * CAP;
    if (t < BROWS) lcnt[t] = 0;
    __syncthreads();
    for (int i = t; i < n; i += 256) atomicAdd(&lcnt[eb[i] >> 17], 1);
    __syncthreads();
    int v = (t < BROWS) ? lcnt[t] : 0;
    if (t < BROWS) sc[t] = v;
    __syncthreads();
    for (int off = 1; off < BROWS; off <<= 1) {
        int a = (t >= off && t < BROWS) ? sc[t - off] : 0;
        __syncthreads();
        if (t < BROWS) sc[t] += a;
        __syncthreads();
    }
    if (t < BROWS) {
        int beg = b * CAP + sc[t] - v;
        gbeg[t] = beg;
        int grow = (b << BUCK_SHIFT) + t;
        if (grow < N_NODES) {
            rowinfo[grow] = make_uint2((unsigned)beg, (unsigned)v);
            dinv[grow] = rsqrtf((float)(v + 1));
            atomicAdd(&ccnt[cl[grow]], 1);
        }
        lcnt[t] = 0;        // reuse as per-row cursor
    }
    __syncthreads();
    for (int i = t; i < n; i += 256) {
        unsigned u = eb[i];
        int lrow = (int)(u >> 17);
        int pos = atomicAdd(&lcnt[lrow], 1);
        csr_col[gbeg[lrow] + pos] = (int)(u & 0x1FFFFu);
    }
}

// ---------------------------------------------------------------- prologue: z = fp16(dinv * (x @ W^T))
// R6 structure (x-row once into registers, W broadcast from LDS, zero
// conflicts) — R7: outputs split into region A (dims 0..31, 64 B rows) and
// region B (dims 32..39, 16 B rows).
__global__ __launch_bounds__(256) void prologue_kernel(
        const float4* __restrict__ x4, const float* __restrict__ W,
        const float* __restrict__ dinv, half_t* __restrict__ zA,
        half_t* __restrict__ zB) {
    __shared__ float Ws[OUT_F * 68];      // 40 rows x 17 float4 (16B-aligned rows)
    int t = threadIdx.x;
    for (int i = t; i < OUT_F * IN_F; i += 256)
        Ws[(i >> 6) * 68 + (i & 63)] = W[i];
    __syncthreads();
    int node = blockIdx.x * 256 + t;
    if (node >= N_NODES) return;
    float4 xr[16];
    const float4* xp = x4 + (size_t)node * 16;
    #pragma unroll
    for (int k = 0; k < 16; ++k) xr[k] = xp[k];
    float d = dinv[node];
    half4_t* zpA = (half4_t*)(zA + (size_t)node * 32);   // 8 half4
    half4_t* zpB = (half4_t*)(zB + (size_t)node * 8);    // 2 half4
    #pragma unroll
    for (int oq = 0; oq < 10; ++oq) {
        half4_t h;
        #pragma unroll
        for (int c = 0; c < 4; ++c) {
            const float4* wr = (const float4*)(Ws + (oq * 4 + c) * 68);
            float acc = 0.f;
            #pragma unroll
            for (int k = 0; k < 16; ++k) {
                float4 wv = wr[k];
                acc += xr[k].x * wv.x + xr[k].y * wv.y
                     + xr[k].z * wv.z + xr[k].w * wv.w;
            }
            h[c] = (half_t)(acc * d);
        }
        if (oq < 8) zpA[oq] = h; else zpB[oq - 8] = h;
    }
}

// ---------------------------------------------------------------- 40-dim fp16 pull hop, 16 nodes/block
// R7: two levers on the measured gather bottleneck (dur tracks (FETCH+WRITE)
// at ~2 TB/s AND request rate was 0.82 req/cy/CU — near the TA ceiling):
//  (1) 16 B/lane loads: row = 5 lanes x half8 (was 10 x half4) => requests/2.
//  (2) split row storage: region A = dims 0..31, 64 B-aligned rows (6.4 MB,
//      never straddles a 128 B line, 2 rows/line => better L2 reuse);
//      region B = dims 32..39, 16 B rows (1.6 MB => ~fully L2-resident).
//      Line-touches/edge drop ~1.5 -> ~1.1, FETCH predicted 90 -> ~55 MB.
// Wave: 12 slots x 5 lanes (lane ql<4 -> A, ql=4 -> B), 4-deep branch-free
// MLP groups (R4), masked accumulate. All trip counts wave-uniform (from
// rowinfo[node], node uniform per wave) => every lane reaches every __shfl
// with all 64 sources active (R8/R9 hazard structurally excluded).
template<int FINAL>
__global__ __launch_bounds__(256, 8) void hop40_kernel(
        const half_t* __restrict__ zinA, const half_t* __restrict__ zinB,
        half_t* __restrict__ zoutA, half_t* __restrict__ zoutB,
        const uint2* __restrict__ rowinfo, const int* __restrict__ csr_col,
        const float* __restrict__ dinv, const int* __restrict__ cl,
        float* __restrict__ xc) {
    __shared__ half8_t srowA[64];         // 16 rows x 4 half8 = 1 KB
    __shared__ half8_t srowB[16];         // 16 rows x 1 half8 = 256 B
    int t = threadIdx.x;
    int w = t >> 6;
    int lane = t & 63;
    int slot = lane / 5;                  // 0..12 ; slot 12 = lanes 60..63 (masked)
    int ql = lane - slot * 5;             // 0..4
    int slotj = (slot < 12) ? slot : 1000;       // masked slots never pass j<lim
    const half_t* gbase = (ql < 4) ? zinA : zinB;
    int gsh  = (ql < 4) ? 5 : 3;          // row stride in halfs: 32 or 8
    int goff = (ql < 4) ? ql * 8 : 0;     // half offset within row
    int nb = blockIdx.x << 4;
    #pragma unroll
    for (int i = 0; i < 4; ++i) {
        int node = nb + (w << 2) + i;
        uint2 ri = rowinfo[node];
        int beg = (int)ri.x;
        int end = beg + (int)ri.y;
        float4 accA = make_float4(0.f, 0.f, 0.f, 0.f);
        float4 accB = make_float4(0.f, 0.f, 0.f, 0.f);
        if (slot == 0) {                  // self-loop
            half8_t v = *(const half8_t*)(gbase + ((size_t)node << gsh) + goff);
            accA.x = (float)v[0]; accA.y = (float)v[1];
            accA.z = (float)v[2]; accA.w = (float)v[3];
            accB.x = (float)v[4]; accB.y = (float)v[5];
            accB.z = (float)v[6]; accB.w = (float)v[7];
        }
        for (int base = beg; base < end; base += 64) {
            int idx = base + lane;
            int cv = (idx < end) ? csr_col[idx] : 0;
            int lim = min(64, end - base);        // wave-uniform (>=1 here)
            int gmax = (lim + 47) / 48;           // wave-uniform; 48 edges/group
            for (int g = 0; g < gmax; ++g) {
                int j0 = g * 48 + slotj;
                int c0 = __shfl(cv, (j0     ) & 63);
                int c1 = __shfl(cv, (j0 + 12) & 63);
                int c2 = __shfl(cv, (j0 + 24) & 63);
                int c3 = __shfl(cv, (j0 + 36) & 63);
                half8_t v0 = *(const half8_t*)(gbase + ((size_t)c0 << gsh) + goff);
                half8_t v1 = *(const half8_t*)(gbase + ((size_t)c1 << gsh) + goff);
                half8_t v2 = *(const half8_t*)(gbase + ((size_t)c2 << gsh) + goff);
                half8_t v3 = *(const half8_t*)(gbase + ((size_t)c3 << gsh) + goff);
                float m0 = (j0      < lim) ? 1.f : 0.f;
                float m1 = (j0 + 12 < lim) ? 1.f : 0.f;
                float m2 = (j0 + 24 < lim) ? 1.f : 0.f;
                float m3 = (j0 + 36 < lim) ? 1.f : 0.f;
                accA.x += m0 * (float)v0[0]; accA.y += m0 * (float)v0[1];
                accA.z += m0 * (float)v0[2]; accA.w += m0 * (float)v0[3];
                accB.x += m0 * (float)v0[4]; accB.y += m0 * (float)v0[5];
                accB.z += m0 * (float)v0[6]; accB.w += m0 * (float)v0[7];
                accA.x += m1 * (float)v1[0]; accA.y += m1 * (float)v1[1];
                accA.z += m1 * (float)v1[2]; accA.w += m1 * (float)v1[3];
                accB.x += m1 * (float)v1[4]; accB.y += m1 * (float)v1[5];
                accB.z += m1 * (float)v1[6]; accB.w += m1 * (float)v1[7];
                accA.x += m2 * (float)v2[0]; accA.y += m2 * (float)v2[1];
                accA.z += m2 * (float)v2[2]; accA.w += m2 * (float)v2[3];
                accB.x += m2 * (float)v2[4]; accB.y += m2 * (float)v2[5];
                accB.z += m2 * (float)v2[6]; accB.w += m2 * (float)v2[7];
                accA.x += m3 * (float)v3[0]; accA.y += m3 * (float)v3[1];
                accA.z += m3 * (float)v3[2]; accA.w += m3 * (float)v3[3];
                accB.x += m3 * (float)v3[4]; accB.y += m3 * (float)v3[5];
                accB.z += m3 * (float)v3[6]; accB.w += m3 * (float)v3[7];
            }
        }
        // reduce 12 slots -> slot 0: fold +30, +15, then +5 and +10
        #define FOLD8(OFF, GUARD)                                            \
        {                                                                    \
            float r0 = __shfl(accA.x, (lane + OFF) & 63);                    \
            float r1 = __shfl(accA.y, (lane + OFF) & 63);                    \
            float r2 = __shfl(accA.z, (lane + OFF) & 63);                    \
            float r3 = __shfl(accA.w, (lane + OFF) & 63);                    \
            float r4 = __shfl(accB.x, (lane + OFF) & 63);                    \
            float r5 = __shfl(accB.y, (lane + OFF) & 63);                    \
            float r6 = __shfl(accB.z, (lane + OFF) & 63);                    \
            float r7 = __shfl(accB.w, (lane + OFF) & 63);                    \
            if (lane < GUARD) {                                              \
                accA.x += r0; accA.y += r1; accA.z += r2; accA.w += r3;      \
                accB.x += r4; accB.y += r5; accB.z += r6; accB.w += r7;      \
            }                                                                \
        }
        FOLD8(30, 30)
        FOLD8(15, 15)
        {
            float s0 = __shfl(accA.x, (lane + 5) & 63),  u0 = __shfl(accA.x, (lane + 10) & 63);
            float s1 = __shfl(accA.y, (lane + 5) & 63),  u1 = __shfl(accA.y, (lane + 10) & 63);
            float s2 = __shfl(accA.z, (lane + 5) & 63),  u2 = __shfl(accA.z, (lane + 10) & 63);
            float s3 = __shfl(accA.w, (lane + 5) & 63),  u3 = __shfl(accA.w, (lane + 10) & 63);
            float s4 = __shfl(accB.x, (lane + 5) & 63),  u4 = __shfl(accB.x, (lane + 10) & 63);
            float s5 = __shfl(accB.y, (lane + 5) & 63),  u5 = __shfl(accB.y, (lane + 10) & 63);
            float s6 = __shfl(accB.z, (lane + 5) & 63),  u6 = __shfl(accB.z, (lane + 10) & 63);
            float s7 = __shfl(accB.w, (lane + 5) & 63),  u7 = __shfl(accB.w, (lane + 10) & 63);
            if (lane < 5) {
                accA.x += s0 + u0; accA.y += s1 + u1; accA.z += s2 + u2; accA.w += s3 + u3;
                accB.x += s4 + u4; accB.y += s5 + u5; accB.z += s6 + u6; accB.w += s7 + u7;
                float d = dinv[node];
                if (FINAL) {
                    float* p = xc + cl[node] * OUT_F + lane * 8;
                    atomicAdd(p + 0, accA.x * d); atomicAdd(p + 1, accA.y * d);
                    atomicAdd(p + 2, accA.z * d); atomicAdd(p + 3, accA.w * d);
                    atomicAdd(p + 4, accB.x * d); atomicAdd(p + 5, accB.y * d);
                    atomicAdd(p + 6, accB.z * d); atomicAdd(p + 7, accB.w * d);
                } else {
                    float s = d * d;
                    half8_t o;
                    o[0] = (half_t)(accA.x * s); o[1] = (half_t)(accA.y * s);
                    o[2] = (half_t)(accA.z * s); o[3] = (half_t)(accA.w * s);
                    o[4] = (half_t)(accB.x * s); o[5] = (half_t)(accB.y * s);
                    o[6] = (half_t)(accB.z * s); o[7] = (half_t)(accB.w * s);
                    int row = (w << 2) + i;
                    if (lane < 4) srowA[row * 4 + lane] = o;
                    else          srowB[row] = o;
                }
            }
        }
        #undef FOLD8
    }
    if (!FINAL) {
        __syncthreads();
        if (t < 64) ((half8_t*)zoutA)[(size_t)blockIdx.x * 64 + t] = srowA[t];
        if (t < 16) ((half8_t*)zoutB)[(size_t)blockIdx.x * 16 + t] = srowB[t];
    }
}

// ---------------------------------------------------------------- epilogue: out[n] = xc[cl[n]]/cnt + b
__global__ void epilogue_kernel(const float4* __restrict__ xc4, const int* __restrict__ ccnt,
                                const float4* __restrict__ b4, const int* __restrict__ cl,
                                float4* __restrict__ out4) {
    int i = blockIdx.x * 256 + threadIdx.x;
    if (i >= N_NODES * (OUT_F / 4)) return;
    int node = i / 10;
    int q = i - node * 10;
    int c = cl[node];
    float inv = 1.0f / fmaxf((float)ccnt[c], 1.0f);
    float4 v = xc4[c * 10 + q];
    float4 bb = b4[q];
    v.x = v.x * inv + bb.x; v.y = v.y * inv + bb.y;
    v.z = v.z * inv + bb.z; v.w = v.w * inv + bb.w;
    out4[i] = v;
}

// ---------------------------------------------------------------- launch
extern "C" void kernel_launch(void* const* d_in, const int* in_sizes, int n_in,
                              void* d_out, int out_size, void* d_ws, size_t ws_size,
                              hipStream_t stream) {
    const float* x    = (const float*)d_in[0];
    const int*   rows = (const int*)d_in[1];
    const int*   cols = (const int*)d_in[1] + N_EDGES;
    const int*   cl   = (const int*)d_in[2];
    const float* W    = (const float*)d_in[4];
    const float* b    = (const float*)d_in[5];
    float* out = (float*)d_out;

    size_t off = 0;
    auto alloc = [&](size_t elems) -> void* {          // 256 B aligned
        void* p = (char*)d_ws + off * 4;
        off += (elems + 63) & ~(size_t)63;
        return p;
    };
    // zeroed region first (single memset): ccnt | xc_sum | bcursor
    int*   ccnt    = (int*)alloc(N_CLUSTERS);
    float* xc_sum  = (float*)alloc((size_t)N_CLUSTERS * OUT_F);
    int*   bcursor = (int*)alloc(NBUCK);
    size_t zero_elems = off;
    float* dinv      = (float*)alloc(N_NODES);
    uint2* rowinfo   = (uint2*)alloc((size_t)N_NODES * 2);
    int*   csr_col   = (int*)alloc((size_t)NBUCK * CAP);             // 8 MB
    unsigned* bins   = (unsigned*)alloc((size_t)NBUCK * CAP);        // 8 MB
    half_t* zA0      = (half_t*)alloc((size_t)N_NODES * 16);         // 6.4 MB (32 dims)
    half_t* zA1      = (half_t*)alloc((size_t)N_NODES * 16);         // 6.4 MB
    half_t* zB0      = (half_t*)alloc((size_t)N_NODES * 4);          // 1.6 MB (8 dims)
    half_t* zB1      = (half_t*)alloc((size_t)N_NODES * 4);          // 1.6 MB
    (void)ws_size; (void)in_sizes; (void)n_in; (void)out_size;

    hipMemsetAsync(d_ws, 0, zero_elems * 4, stream);

    const int TB = (N_EDGES + TILE_E - 1) / TILE_E;   // 391
    const int HB = N_NODES / 16;                      // 6250

    bin_scatter_kernel<<<TB, 256, 0, stream>>>(rows, cols, bcursor, bins);
    csr_build_kernel<<<NBUCK, 256, 0, stream>>>(bins, bcursor, csr_col, rowinfo,
                                                dinv, cl, ccnt);

    prologue_kernel<<<(N_NODES + 255) / 256, 256, 0, stream>>>(
        (const float4*)x, W, dinv, zA0, zB0);

    hop40_kernel<0><<<HB, 256, 0, stream>>>(zA0, zB0, zA1, zB1, rowinfo, csr_col, dinv, cl, xc_sum);
    hop40_kernel<0><<<HB, 256, 0, stream>>>(zA1, zB1, zA0, zB0, rowinfo, csr_col, dinv, cl, xc_sum);
    hop40_kernel<1><<<HB, 256, 0, stream>>>(zA0, zB0, (half_t*)nullptr, (half_t*)nullptr,
                                            rowinfo, csr_col, dinv, cl, xc_sum);

    epilogue_kernel<<<(N_NODES * (OUT_F / 4) + 255) / 256, 256, 0, stream>>>(
        (const float4*)xc_sum, ccnt, (const float4*)b, cl, (float4*)out);
}